// Round 13
// baseline (29.176 us; speedup 1.0000x reference)
//
#include <hip/hip_runtime.h>

#define BB 64
#define SS 512
#define DD 768
#define D4 192   // DD/4

typedef float v4f __attribute__((ext_vector_type(4)));

// Kernel A (R12-proven, BG=2 line-exact): tW[b][d] = sum_k topic[b][k]*W[k][d]
// grid (32, 24), block 256. Each block: 2 b's, 32 d's, full K=768.
// dl=t&7 -> one full 128B line per row-segment; kg=t>>3 -> 32 chains of 24.
__global__ void tw_kernel(const float* __restrict__ topic,
                          const float* __restrict__ W,
                          float* __restrict__ tW) {
    __shared__ float  t_s[2][DD];          // 6 KB
    __shared__ float4 red[4][2][8];        // 1 KB
    const int t    = threadIdx.x;
    const int b0   = blockIdx.x * 2;
    const int d4   = blockIdx.y * 8;       // tile start in float4 units
    const int dl   = t & 7;
    const int kg   = t >> 3;               // 0..31
    const int wv   = t >> 6;               // 0..3
    const int lane = t & 63;

    {
        const float4* tp  = (const float4*)topic + (size_t)b0 * D4;
        float4*       ts4 = (float4*)t_s;
        ts4[t] = tp[t];
        if (t < 128) ts4[t + 256] = tp[t + 256];
    }
    __syncthreads();

    const float4* __restrict__ W4 = (const float4*)W;  // [DD][D4]
    const int k0 = kg * 24;
    float4 a0 = make_float4(0.f, 0.f, 0.f, 0.f);
    float4 a1 = make_float4(0.f, 0.f, 0.f, 0.f);

#pragma unroll
    for (int k = 0; k < 24; ++k) {
        const float4 w  = W4[(size_t)(k0 + k) * D4 + d4 + dl];
        const float  s0 = t_s[0][k0 + k];
        const float  s1 = t_s[1][k0 + k];
        a0.x = fmaf(s0, w.x, a0.x); a0.y = fmaf(s0, w.y, a0.y);
        a0.z = fmaf(s0, w.z, a0.z); a0.w = fmaf(s0, w.w, a0.w);
        a1.x = fmaf(s1, w.x, a1.x); a1.y = fmaf(s1, w.y, a1.y);
        a1.z = fmaf(s1, w.z, a1.z); a1.w = fmaf(s1, w.w, a1.w);
    }

#pragma unroll
    for (int off = 8; off <= 32; off <<= 1) {
        a0.x += __shfl_xor(a0.x, off); a0.y += __shfl_xor(a0.y, off);
        a0.z += __shfl_xor(a0.z, off); a0.w += __shfl_xor(a0.w, off);
        a1.x += __shfl_xor(a1.x, off); a1.y += __shfl_xor(a1.y, off);
        a1.z += __shfl_xor(a1.z, off); a1.w += __shfl_xor(a1.w, off);
    }
    if (lane < 8) {                        // lane == dl here
        red[wv][0][lane] = a0;
        red[wv][1][lane] = a1;
    }
    __syncthreads();

    if (t < 16) {
        const int bi = t >> 3, d = t & 7;
        const float4 s0 = red[0][bi][d], s1 = red[1][bi][d];
        const float4 s2 = red[2][bi][d], s3 = red[3][bi][d];
        float4 s;
        s.x = (s0.x + s1.x) + (s2.x + s3.x);
        s.y = (s0.y + s1.y) + (s2.y + s3.y);
        s.z = (s0.z + s1.z) + (s2.z + s3.z);
        s.w = (s0.w + s1.w) + (s2.w + s3.w);
        ((float4*)tW)[(size_t)(b0 + bi) * D4 + d4 + d] = s;
    }
}

// Kernel B v5: one wave per FOUR scores. tW row hoisted to regs once per wave
// (tW cache traffic 100->25 MB, VMEM issues per score 6 -> 3.75), seq loads
// nontemporal, one float4 store per wave. Bias dropped: softmax is
// shift-invariant, so softmax(scores + b) == softmax(scores) exactly.
__global__ void score_kernel(const float* __restrict__ tW,
                             const float* __restrict__ seq,
                             float* __restrict__ scores) {
    const int gwid = (int)((blockIdx.x * blockDim.x + threadIdx.x) >> 6);
    const int lane = threadIdx.x & 63;
    const int b  = gwid >> 7;           // 128 waves per b
    const int s0 = (gwid & 127) << 2;   // 4 consecutive s per wave

    const float4* tp = (const float4*)(tW + (size_t)b * DD);
    const float4 t0 = tp[lane];
    const float4 t1 = tp[lane + 64];
    const float4 t2 = tp[lane + 128];

    const v4f* sp = (const v4f*)(seq + ((size_t)b * SS + s0) * DD);

    float acc[4];
#pragma unroll
    for (int i = 0; i < 4; ++i) {
        const v4f x0 = __builtin_nontemporal_load(sp + i * D4 + lane);
        const v4f x1 = __builtin_nontemporal_load(sp + i * D4 + lane + 64);
        const v4f x2 = __builtin_nontemporal_load(sp + i * D4 + lane + 128);
        float a = 0.f;
        a = fmaf(x0.x, t0.x, a); a = fmaf(x0.y, t0.y, a);
        a = fmaf(x0.z, t0.z, a); a = fmaf(x0.w, t0.w, a);
        a = fmaf(x1.x, t1.x, a); a = fmaf(x1.y, t1.y, a);
        a = fmaf(x1.z, t1.z, a); a = fmaf(x1.w, t1.w, a);
        a = fmaf(x2.x, t2.x, a); a = fmaf(x2.y, t2.y, a);
        a = fmaf(x2.z, t2.z, a); a = fmaf(x2.w, t2.w, a);
        acc[i] = a;
    }

#pragma unroll
    for (int i = 0; i < 4; ++i)
#pragma unroll
        for (int off = 32; off >= 1; off >>= 1) acc[i] += __shfl_xor(acc[i], off);

    if (lane == 0) {
        float4 r = make_float4(acc[0], acc[1], acc[2], acc[3]);
        *(float4*)(scores + (size_t)b * SS + s0) = r;
    }
}

// Kernel C: beta[b] = softmax(scores[b]) over S. One block of 512 per b.
__global__ void softmax_kernel(const float* __restrict__ scores,
                               float* __restrict__ beta) {
    __shared__ float red[8];
    __shared__ float s_m, s_sum;
    const int b   = blockIdx.x;
    const int tid = threadIdx.x;          // 0..511
    const int wid = tid >> 6, lane = tid & 63;

    const float v = scores[b * SS + tid];

    float m = v;
#pragma unroll
    for (int off = 32; off >= 1; off >>= 1) m = fmaxf(m, __shfl_xor(m, off));
    if (lane == 0) red[wid] = m;
    __syncthreads();
    if (tid == 0) {
        float mm = red[0];
#pragma unroll
        for (int i = 1; i < 8; ++i) mm = fmaxf(mm, red[i]);
        s_m = mm;
    }
    __syncthreads();

    const float e = __expf(v - s_m);
    float sum = e;
#pragma unroll
    for (int off = 32; off >= 1; off >>= 1) sum += __shfl_xor(sum, off);
    if (lane == 0) red[wid] = sum;
    __syncthreads();
    if (tid == 0) {
        float ss = 0.f;
#pragma unroll
        for (int i = 0; i < 8; ++i) ss += red[i];
        s_sum = ss;
    }
    __syncthreads();

    beta[b * SS + tid] = e / s_sum;
}

extern "C" void kernel_launch(void* const* d_in, const int* in_sizes, int n_in,
                              void* d_out, int out_size, void* d_ws, size_t ws_size,
                              hipStream_t stream) {
    const float* topic = (const float*)d_in[0];
    const float* seq   = (const float*)d_in[1];
    const float* W     = (const float*)d_in[2];
    float* out = (float*)d_out;

    float* tW     = (float*)d_ws;                 // BB*DD floats
    float* scores = tW + (size_t)BB * DD;         // BB*SS floats

    tw_kernel<<<dim3(BB / 2, 24), 256, 0, stream>>>(topic, W, tW);

    const int total_waves = (BB * SS) / 4;        // one wave per 4 scores
    const int blocks = (total_waves * 64) / 256;  // 2048 blocks, 8/CU
    score_kernel<<<blocks, 256, 0, stream>>>(tW, seq, scores);

    softmax_kernel<<<BB, 512, 0, stream>>>(scores, out);
}

// Round 14
// 28.234 us; speedup vs baseline: 1.0334x; 1.0334x over previous
//
#include <hip/hip_runtime.h>

#define BB 64
#define SS 512
#define DD 768
#define D4 192   // DD/4

typedef float v4f __attribute__((ext_vector_type(4)));

// Kernel A (BG=2, line-exact): tW[b][d] = sum_k topic[b][k] * W[k][d]
// grid (32, 24), block 256. Each block: 2 b's, 32 d's (8 float4), full K=768.
// dl=t&7 -> 8 lanes x 16B = one full 128B line per row-segment (128B-aligned).
// kg=t>>3 -> 32 k-chains of 24, fully unrolled (24 loads in flight).
// 768 blocks (even 3/CU) AND 2x W-reuse (75.5 MB L2 traffic).
__global__ void tw_kernel(const float* __restrict__ topic,
                          const float* __restrict__ W,
                          float* __restrict__ tW) {
    __shared__ float  t_s[2][DD];          // 6 KB
    __shared__ float4 red[4][2][8];        // 1 KB
    const int t    = threadIdx.x;
    const int b0   = blockIdx.x * 2;
    const int d4   = blockIdx.y * 8;       // tile start in float4 units
    const int dl   = t & 7;
    const int kg   = t >> 3;               // 0..31
    const int wv   = t >> 6;               // 0..3
    const int lane = t & 63;

    // stage 2 contiguous topic rows (384 float4s)
    {
        const float4* tp  = (const float4*)topic + (size_t)b0 * D4;
        float4*       ts4 = (float4*)t_s;
        ts4[t] = tp[t];
        if (t < 128) ts4[t + 256] = tp[t + 256];
    }
    __syncthreads();

    const float4* __restrict__ W4 = (const float4*)W;  // [DD][D4]
    const int k0 = kg * 24;
    float4 a0 = make_float4(0.f, 0.f, 0.f, 0.f);
    float4 a1 = make_float4(0.f, 0.f, 0.f, 0.f);

#pragma unroll
    for (int k = 0; k < 24; ++k) {
        const float4 w  = W4[(size_t)(k0 + k) * D4 + d4 + dl];
        const float  s0 = t_s[0][k0 + k];
        const float  s1 = t_s[1][k0 + k];
        a0.x = fmaf(s0, w.x, a0.x); a0.y = fmaf(s0, w.y, a0.y);
        a0.z = fmaf(s0, w.z, a0.z); a0.w = fmaf(s0, w.w, a0.w);
        a1.x = fmaf(s1, w.x, a1.x); a1.y = fmaf(s1, w.y, a1.y);
        a1.z = fmaf(s1, w.z, a1.z); a1.w = fmaf(s1, w.w, a1.w);
    }

    // in-wave reduce across the 8 kg's resident in this wave (lane bits 3..5)
#pragma unroll
    for (int off = 8; off <= 32; off <<= 1) {
        a0.x += __shfl_xor(a0.x, off); a0.y += __shfl_xor(a0.y, off);
        a0.z += __shfl_xor(a0.z, off); a0.w += __shfl_xor(a0.w, off);
        a1.x += __shfl_xor(a1.x, off); a1.y += __shfl_xor(a1.y, off);
        a1.z += __shfl_xor(a1.z, off); a1.w += __shfl_xor(a1.w, off);
    }
    if (lane < 8) {                        // lane == dl here
        red[wv][0][lane] = a0;
        red[wv][1][lane] = a1;
    }
    __syncthreads();

    if (t < 16) {
        const int bi = t >> 3, d = t & 7;
        const float4 s0 = red[0][bi][d], s1 = red[1][bi][d];
        const float4 s2 = red[2][bi][d], s3 = red[3][bi][d];
        float4 s;
        s.x = (s0.x + s1.x) + (s2.x + s3.x);
        s.y = (s0.y + s1.y) + (s2.y + s3.y);
        s.z = (s0.z + s1.z) + (s2.z + s3.z);
        s.w = (s0.w + s1.w) + (s2.w + s3.w);
        ((float4*)tW)[(size_t)(b0 + bi) * D4 + d4 + d] = s;
    }
}

// Kernel B: scores[b][s] = dot(tW[b], seq[b][s]) + bias   (R4-proven, byte-identical)
__global__ void score_kernel(const float* __restrict__ tW,
                             const float* __restrict__ seq,
                             const float* __restrict__ bias,
                             float* __restrict__ scores) {
    const int gwid = (int)((blockIdx.x * blockDim.x + threadIdx.x) >> 6);
    const int lane = threadIdx.x & 63;
    const int b = gwid >> 9;      // / SS
    const int s = gwid & (SS - 1);

    const v4f* sp = (const v4f*)(seq + ((size_t)b * SS + s) * DD);
    const float4* tp = (const float4*)(tW + (size_t)b * DD);

    float acc = 0.f;
#pragma unroll
    for (int k = 0; k < 3; ++k) {
        const v4f x = __builtin_nontemporal_load(sp + lane + k * 64);
        const float4 t = tp[lane + k * 64];
        acc = fmaf(x.x, t.x, acc);
        acc = fmaf(x.y, t.y, acc);
        acc = fmaf(x.z, t.z, acc);
        acc = fmaf(x.w, t.w, acc);
    }
#pragma unroll
    for (int off = 32; off >= 1; off >>= 1) acc += __shfl_xor(acc, off);

    if (lane == 0) scores[gwid] = acc + bias[0];
}

// Kernel C: beta[b] = softmax(scores[b]) over S. One block of 512 per b.
__global__ void softmax_kernel(const float* __restrict__ scores,
                               float* __restrict__ beta) {
    __shared__ float red[8];
    __shared__ float s_m, s_sum;
    const int b   = blockIdx.x;
    const int tid = threadIdx.x;          // 0..511
    const int wid = tid >> 6, lane = tid & 63;

    const float v = scores[b * SS + tid];

    float m = v;
#pragma unroll
    for (int off = 32; off >= 1; off >>= 1) m = fmaxf(m, __shfl_xor(m, off));
    if (lane == 0) red[wid] = m;
    __syncthreads();
    if (tid == 0) {
        float mm = red[0];
#pragma unroll
        for (int i = 1; i < 8; ++i) mm = fmaxf(mm, red[i]);
        s_m = mm;
    }
    __syncthreads();

    const float e = __expf(v - s_m);
    float sum = e;
#pragma unroll
    for (int off = 32; off >= 1; off >>= 1) sum += __shfl_xor(sum, off);
    if (lane == 0) red[wid] = sum;
    __syncthreads();
    if (tid == 0) {
        float ss = 0.f;
#pragma unroll
        for (int i = 0; i < 8; ++i) ss += red[i];
        s_sum = ss;
    }
    __syncthreads();

    beta[b * SS + tid] = e / s_sum;
}

extern "C" void kernel_launch(void* const* d_in, const int* in_sizes, int n_in,
                              void* d_out, int out_size, void* d_ws, size_t ws_size,
                              hipStream_t stream) {
    const float* topic = (const float*)d_in[0];
    const float* seq   = (const float*)d_in[1];
    const float* W     = (const float*)d_in[2];
    const float* bias  = (const float*)d_in[3];
    float* out = (float*)d_out;

    float* tW     = (float*)d_ws;                 // BB*DD floats
    float* scores = tW + (size_t)BB * DD;         // BB*SS floats

    tw_kernel<<<dim3(BB / 2, 24), 256, 0, stream>>>(topic, W, tW);

    const int total_waves = BB * SS;              // one wave per score
    const int blocks = (total_waves * 64) / 256;  // 4 waves per block
    score_kernel<<<blocks, 256, 0, stream>>>(tW, seq, bias, scores);

    softmax_kernel<<<BB, 512, 0, stream>>>(scores, out);
}